// Round 12
// baseline (60.701 us; speedup 1.0000x reference)
//
#include <hip/hip_runtime.h>

// Plenoxels: trilinear voxel interp (192^3 x 28 ch) + SH deg-2 eval.
// R12: LINE-COALESCED gather. R9/R10/R11 nulls localize the wall to
// coalescer-granular transactions: every prior gather instr had 64 lanes on
// 64 distinct cells (~64 lines -> 56 trans/pt). Now 4 lanes per cell
// (2 points per instr, 16 cells): ~22 lines/instr -> 22 trans/pt (2.55x).
// Lane (pt=lane>>5, cell j=(lane>>2)&7, q=lane&3):
//   k=0: dwordx4 @ cell+16q  (ch 4q..4q+3)
//   k=1 (q<3): dwordx4 @ cell+64+16q (ch 16+4q..19+4q)
// Per-lane partial SH via static switch on q; *wj; reduce q (2 DPP) +
// cells (3 shfl_xor). Weight/corner LUTs + sum-before-relu unchanged.
// Phase 1 identical to validated R10/R11.

#define VNL 192
#define BLK 256
#define WPB 4
#define TILES 4
#define PTS (BLK * TILES)   // 1024 points per block

#define SH_C0f 0.28209479177387814f
#define SH_C1f 0.4886025119029199f
#define C2_0f  1.0925484305920792f
#define C2_1f (-1.0925484305920792f)
#define C2_2f  0.31539156525252005f
#define C2_3f (-1.0925484305920792f)
#define C2_4f  0.5462742152960396f

template <int CTRL>
__device__ __forceinline__ float dpp_add(float v) {
    int s = __builtin_amdgcn_update_dpp(0, __float_as_int(v), CTRL, 0xF, 0xF, true);
    return v + __int_as_float(s);
}

__global__ __launch_bounds__(BLK) void plen_fused_kernel(
    const float* __restrict__ x,
    const float* __restrict__ d,
    const float* __restrict__ voxel,
    float* __restrict__ out,
    int N)
{
    __shared__ __align__(16) float4 s_pool[PTS][2];     // 32 KB record pool
    __shared__ __align__(16) float  s_xbuf[3 * PTS];    // 12 KB x staging
    __shared__ unsigned s_wcnt[TILES][WPB];

    const int tid  = threadIdx.x;
    const int wid  = tid >> 6;
    const int lane = tid & 63;
    const int base_i = blockIdx.x * PTS;
    const int rem = N - base_i;
    const bool full = (rem >= PTS);

    const float4 z4 = make_float4(0.f, 0.f, 0.f, 0.f);

    // ---- zero this block's output range (float4; actives overwritten later) --
    if (full && (((3 * base_i) & 3) == 0)) {
        float4* cf4 = reinterpret_cast<float4*>(out) + ((3 * base_i) >> 2);
        #pragma unroll
        for (int k = 0; k < 3; ++k) cf4[k * BLK + tid] = z4;
    } else {
        for (int k = tid; k < 3 * (rem < PTS ? rem : PTS); k += BLK)
            out[3 * base_i + k] = 0.f;
    }
    if (full && (((3 * N + base_i) & 3) == 0)) {
        float4* sf4 = reinterpret_cast<float4*>(out + (size_t)3 * N + base_i);
        sf4[tid] = z4;
    } else {
        for (int k = tid; k < (rem < PTS ? rem : PTS); k += BLK)
            out[(size_t)3 * N + base_i + k] = 0.f;
    }

    // ---- stage x for the whole block via float4 loads ----------------------
    if (full && (((3 * base_i) & 3) == 0)) {
        const float4* xf4 = reinterpret_cast<const float4*>(x) + ((3 * base_i) >> 2);
        float4* sb4 = reinterpret_cast<float4*>(s_xbuf);
        #pragma unroll
        for (int k = 0; k < 3; ++k) sb4[k * BLK + tid] = xf4[k * BLK + tid];
    } else {
        for (int k = tid; k < 3 * (rem < PTS ? rem : PTS); k += BLK)
            s_xbuf[k] = x[3 * base_i + k];
    }
    __syncthreads();

    // ---- phase 1: mask + records (d loaded exec-masked, actives only) ------
    unsigned Mrun = 0;
    for (int t = 0; t < TILES; ++t) {
        int p = t * BLK + tid;
        int i = base_i + p;
        bool act = false;
        float ix = 0.f, iy = 0.f, iz = 0.f;
        float vdx = 0.f, vdy = 0.f, vdz = 0.f;
        if (i < N) {
            float px = s_xbuf[3 * p + 0] / 1.5f;
            float py = s_xbuf[3 * p + 1] / 1.5f;
            float pz = s_xbuf[3 * p + 2] / 1.5f;
            act = (fabsf(px) < 0.5f) && (fabsf(py) < 0.5f) && (fabsf(pz) < 0.5f);
            if (act) {
                const float step = 2.0f / (float)VNL;
                ix = fminf(fmaxf(px / step + (float)(VNL / 2), 0.0f), (float)(VNL - 1));
                iy = fminf(fmaxf(py / step + (float)(VNL / 2), 0.0f), (float)(VNL - 1));
                iz = fminf(fmaxf(pz / step + (float)(VNL / 2), 0.0f), (float)(VNL - 1));
                vdx = d[3 * i + 0];
                vdy = d[3 * i + 1];
                vdz = d[3 * i + 2];
            }
        }

        unsigned long long bal = __ballot(act);
        unsigned wtot = (unsigned)__popcll(bal);
        unsigned pre  = (unsigned)__popcll(bal & ((1ull << lane) - 1ull));
        if (lane == 0) s_wcnt[t][wid] = wtot;
        __syncthreads();

        unsigned n0 = s_wcnt[t][0], n1 = s_wcnt[t][1];
        unsigned n2 = s_wcnt[t][2], n3 = s_wcnt[t][3];
        unsigned wbase = Mrun + (wid > 0 ? n0 : 0u) + (wid > 1 ? n1 : 0u)
                              + (wid > 2 ? n2 : 0u);
        if (act) {
            unsigned slot = wbase + pre;
            s_pool[slot][0] = make_float4(ix, iy, iz, __int_as_float(i));
            s_pool[slot][1] = make_float4(vdx, vdy, vdz, 0.f);
        }
        Mrun += n0 + n1 + n2 + n3;
    }
    __syncthreads();

    // ---- phase 2: line-coalesced gather (2 points per iteration/wave) ------
    const unsigned M = Mrun;
    if (M == 0) return;
    const unsigned npair = (M + 1u) >> 1;

    const int jj = (lane >> 2) & 7;   // cell/corner 0..7
    const int q  = lane & 3;          // quarter within cell

    for (unsigned pr = (unsigned)wid; pr < npair; pr += WPB) {
        unsigned p = 2u * pr + (unsigned)(lane >> 5);   // half 0/1 -> point
        bool on = (p < M);
        unsigned pc = on ? p : (M - 1u);

        float4 e0 = s_pool[pc][0];    // (ix,iy,iz, i)  uniform per 32-half
        float4 e1 = s_pool[pc][1];    // (dx,dy,dz, -)

        float fx = floorf(e0.x), fy = floorf(e0.y), fz = floorf(e0.z);
        int f0i = (int)fx, f1i = (int)fy, f2i = (int)fz;
        int c0i = (int)ceilf(e0.x), c1i = (int)ceilf(e0.y), c2i = (int)ceilf(e0.z);
        float t0 = e0.x - fx, t1 = e0.y - fy, t2 = e0.z - fz;

        // validated non-standard weight pairing + corner tables (R6+)
        float wj = ((jj & 4) ? t2 : 1.0f - t2) * ((jj & 2) ? t1 : 1.0f - t1)
                 * ((jj & 1) ? t0 : 1.0f - t0);
        int X = ((0xE2 >> jj) & 1) ? c0i : f0i;
        int Y = ((0xD4 >> jj) & 1) ? c1i : f1i;
        int Z = ((0xB8 >> jj) & 1) ? c2i : f2i;
        const char* cell = (const char*)voxel
            + (size_t)(unsigned)(((X * VNL + Y) * VNL + Z) * 112);

        // two coalesced loads: 16 cells per instruction
        float4 va = *(const float4*)(cell + 16 * q);           // ch 4q..4q+3
        float4 vb = z4;
        if (q < 3) vb = *(const float4*)(cell + 64 + 16 * q);  // ch 16+4q..19+4q

        float pdx = e1.x, pdy = e1.y, pdz = e1.z;
        float b1 = -SH_C1f * pdy;
        float b2 =  SH_C1f * pdz;
        float b3 = -SH_C1f * pdx;
        float b4 = C2_0f * pdx * pdy;
        float b5 = C2_1f * pdy * pdz;
        float b6 = C2_2f * (2.0f * pdz * pdz - pdx * pdx - pdy * pdy);
        float b7 = C2_3f * pdx * pdz;
        float b8 = C2_4f * (pdx * pdx - pdy * pdy);

        // per-lane 4-channel partials (static per q; no dynamic indexing)
        float f0a = 0.f, cc0 = 0.f, cc1 = 0.f, cc2 = 0.f;
        switch (q) {
        case 0:   // k0: ch0..3 ; k1: ch16..19
            f0a = va.x;
            cc0 = SH_C0f * va.y + b1 * va.z + b2 * va.w;
            cc1 = b6 * vb.x + b7 * vb.y + b8 * vb.z;
            cc2 = SH_C0f * vb.w;
            break;
        case 1:   // k0: ch4..7 ; k1: ch20..23
            cc0 = b3 * va.x + b4 * va.y + b5 * va.z + b6 * va.w;
            cc2 = b1 * vb.x + b2 * vb.y + b3 * vb.z + b4 * vb.w;
            break;
        case 2:   // k0: ch8..11 ; k1: ch24..27
            cc0 = b7 * va.x + b8 * va.y;
            cc1 = SH_C0f * va.z + b1 * va.w;
            cc2 = b5 * vb.x + b6 * vb.y + b7 * vb.z + b8 * vb.w;
            break;
        default:  // q==3, k0: ch12..15 ; k1: none
            cc1 = b2 * va.x + b3 * va.y + b4 * va.z + b5 * va.w;
            break;
        }
        f0a *= wj; cc0 *= wj; cc1 *= wj; cc2 *= wj;

        // reduce: q (strides 1,2 via DPP quad) then cells (4,8,16 via shfl_xor)
        f0a = dpp_add<0xB1>(f0a); cc0 = dpp_add<0xB1>(cc0);
        cc1 = dpp_add<0xB1>(cc1); cc2 = dpp_add<0xB1>(cc2);
        f0a = dpp_add<0x4E>(f0a); cc0 = dpp_add<0x4E>(cc0);
        cc1 = dpp_add<0x4E>(cc1); cc2 = dpp_add<0x4E>(cc2);
        #pragma unroll
        for (int m = 4; m <= 16; m <<= 1) {
            f0a += __shfl_xor(f0a, m);
            cc0 += __shfl_xor(cc0, m);
            cc1 += __shfl_xor(cc1, m);
            cc2 += __shfl_xor(cc2, m);
        }

        int sub = lane & 31;          // 0..3 stores; rest idle
        if (on && sub < 4) {
            int pi = __float_as_int(e0.w);
            float rv = (sub == 0) ? cc0 : (sub == 1) ? cc1 : (sub == 2) ? cc2
                                                          : fmaxf(f0a, 0.0f);
            size_t a = (sub < 3) ? ((size_t)3 * pi + sub) : ((size_t)3 * N + pi);
            out[a] = rv;
        }
    }
}

extern "C" void kernel_launch(void* const* d_in, const int* in_sizes, int n_in,
                              void* d_out, int out_size, void* d_ws, size_t ws_size,
                              hipStream_t stream) {
    const float* x     = (const float*)d_in[0];
    const float* d     = (const float*)d_in[1];
    const float* voxel = (const float*)d_in[2];
    float* out = (float*)d_out;
    int N = in_sizes[0] / 3;

    int grid = (N + PTS - 1) / PTS;
    plen_fused_kernel<<<grid, BLK, 0, stream>>>(x, d, voxel, out, N);
}

// Round 14
// 45.591 us; speedup vs baseline: 1.3314x; 1.3314x over previous
//
#include <hip/hip_runtime.h>

// Plenoxels: trilinear voxel interp (192^3 x 28 ch) + SH deg-2 eval.
// R14 = R13 (occupancy probe: TILES=2, 22KB LDS, ~7 blocks/CU) with the R13
// prologue overrun FIXED: color/sigma zeroing and x staging use guarded
// k<3*PTS/4 loops instead of the broken 3*TILES/2 unroll that wrote 2x past
// the block range (crash). Gather/SH/reduce semantics identical to R11.

#define VNL 192
#define BLK 256
#define WPB 4
#define TILES 2
#define PTS (BLK * TILES)   // 512 points per block

#define SH_C0f 0.28209479177387814f
#define SH_C1f 0.4886025119029199f
#define C2_0f  1.0925484305920792f
#define C2_1f (-1.0925484305920792f)
#define C2_2f  0.31539156525252005f
#define C2_3f (-1.0925484305920792f)
#define C2_4f  0.5462742152960396f

template <int CTRL>
__device__ __forceinline__ float dpp_add(float v) {
    int s = __builtin_amdgcn_update_dpp(0, __float_as_int(v), CTRL, 0xF, 0xF, true);
    return v + __int_as_float(s);
}

__global__ __launch_bounds__(BLK) void plen_fused_kernel(
    const float* __restrict__ x,
    const float* __restrict__ d,
    const float* __restrict__ voxel,
    float* __restrict__ out,
    int N)
{
    __shared__ __align__(16) float4 s_pool[PTS][2];     // 16 KB record pool
    __shared__ __align__(16) float  s_xbuf[3 * PTS];    // 6 KB x staging
    __shared__ unsigned s_wcnt[TILES][WPB];

    const int tid  = threadIdx.x;
    const int wid  = tid >> 6;
    const int lane = tid & 63;
    const int g = lane >> 3;   // group 0..7
    const int j = lane & 7;    // slot 0..7 within group
    const int base_i = blockIdx.x * PTS;
    const int rem = N - base_i;
    const bool full = (rem >= PTS);

    const float4 z4 = make_float4(0.f, 0.f, 0.f, 0.f);

    // ---- zero this block's output range (actives overwritten after barrier) --
    if (full && (((3 * base_i) & 3) == 0)) {
        float4* cf4 = reinterpret_cast<float4*>(out) + ((3 * base_i) >> 2);
        for (int k = tid; k < 3 * PTS / 4; k += BLK) cf4[k] = z4;   // 384 f4
    } else {
        int lim = 3 * (rem < PTS ? rem : PTS);
        for (int k = tid; k < lim; k += BLK) out[3 * base_i + k] = 0.f;
    }
    if (full && (((3 * (long long)N + base_i) & 3) == 0)) {
        float4* sf4 = reinterpret_cast<float4*>(out + (size_t)3 * N + base_i);
        for (int k = tid; k < PTS / 4; k += BLK) sf4[k] = z4;       // 128 f4
    } else {
        int lim = (rem < PTS ? rem : PTS);
        for (int k = tid; k < lim; k += BLK) out[(size_t)3 * N + base_i + k] = 0.f;
    }

    // ---- stage x for the whole block via float4 loads ----------------------
    if (full && (((3 * base_i) & 3) == 0)) {
        const float4* xf4 = reinterpret_cast<const float4*>(x) + ((3 * base_i) >> 2);
        float4* sb4 = reinterpret_cast<float4*>(s_xbuf);
        for (int k = tid; k < 3 * PTS / 4; k += BLK) sb4[k] = xf4[k]; // 384 f4
    } else {
        int lim = 3 * (rem < PTS ? rem : PTS);
        for (int k = tid; k < lim; k += BLK) s_xbuf[k] = x[3 * base_i + k];
    }
    __syncthreads();

    // ---- phase 1: mask + records (d loaded exec-masked, actives only) ------
    unsigned Mrun = 0;
    for (int t = 0; t < TILES; ++t) {
        int p = t * BLK + tid;
        int i = base_i + p;
        bool act = false;
        float ix = 0.f, iy = 0.f, iz = 0.f;
        float vdx = 0.f, vdy = 0.f, vdz = 0.f;
        if (i < N) {
            float px = s_xbuf[3 * p + 0] / 1.5f;
            float py = s_xbuf[3 * p + 1] / 1.5f;
            float pz = s_xbuf[3 * p + 2] / 1.5f;
            act = (fabsf(px) < 0.5f) && (fabsf(py) < 0.5f) && (fabsf(pz) < 0.5f);
            if (act) {
                const float step = 2.0f / (float)VNL;
                ix = fminf(fmaxf(px / step + (float)(VNL / 2), 0.0f), (float)(VNL - 1));
                iy = fminf(fmaxf(py / step + (float)(VNL / 2), 0.0f), (float)(VNL - 1));
                iz = fminf(fmaxf(pz / step + (float)(VNL / 2), 0.0f), (float)(VNL - 1));
                vdx = d[3 * i + 0];
                vdy = d[3 * i + 1];
                vdz = d[3 * i + 2];
            }
        }

        unsigned long long bal = __ballot(act);
        unsigned wtot = (unsigned)__popcll(bal);
        unsigned pre  = (unsigned)__popcll(bal & ((1ull << lane) - 1ull));
        if (lane == 0) s_wcnt[t][wid] = wtot;
        __syncthreads();

        unsigned n0 = s_wcnt[t][0], n1 = s_wcnt[t][1];
        unsigned n2 = s_wcnt[t][2], n3 = s_wcnt[t][3];
        unsigned wbase = Mrun + (wid > 0 ? n0 : 0u) + (wid > 1 ? n1 : 0u)
                              + (wid > 2 ? n2 : 0u);
        if (act) {
            unsigned slot = wbase + pre;
            s_pool[slot][0] = make_float4(ix, iy, iz, __int_as_float(i));
            s_pool[slot][1] = make_float4(vdx, vdy, vdz, 0.f);
        }
        Mrun += n0 + n1 + n2 + n3;
    }
    __syncthreads();

    // ---- phase 2: z-pair gather + SH + DPP reduce (validated R11) ----------
    const unsigned M = Mrun;
    if (M == 0) return;
    const unsigned nch = (M + 7u) >> 3;

    // lane slot j -> original corner index j_old (preserves validated weights)
    const int jo = (int)((0x76425130u >> (4 * j)) & 7u);
    const int r  = j >> 1;      // z-pair run 0..3
    const int h  = j & 1;       // half within run (0: z=f2, 1: z=c2)

    for (unsigned c = (unsigned)wid; c < nch; c += WPB) {
        unsigned rr = c * 8u + (unsigned)g;
        bool on = (rr < M);
        unsigned rc = on ? rr : (M - 1u);

        float4 e0 = s_pool[rc][0];     // (ix,iy,iz, i)  LDS group-broadcast
        float4 e1 = s_pool[rc][1];     // (dx,dy,dz, -)

        float fx = floorf(e0.x), fy = floorf(e0.y), fz = floorf(e0.z);
        int f0 = (int)fx, f1 = (int)fy, f2 = (int)fz;
        int c0i = (int)ceilf(e0.x), c1i = (int)ceilf(e0.y), c2i = (int)ceilf(e0.z);
        float t0 = e0.x - fx, t1 = e0.y - fy, t2 = e0.z - fz;

        // validated non-standard weight pairing, keyed by original corner jo
        float wj = ((jo & 4) ? t2 : 1.0f - t2) * ((jo & 2) ? t1 : 1.0f - t1)
                 * ((jo & 1) ? t0 : 1.0f - t0);

        // run coords: X/Y per run table {(f,f),(c,f),(f,c),(c,c)}; z = f2 + h*(c2-f2)
        int X = (r & 1) ? c0i : f0;
        int Y = (r & 2) ? c1i : f1;
        const char* cell = (const char*)voxel
            + (size_t)(unsigned)(((X * VNL + Y) * VNL + f2) * 112 + h * (c2i - f2) * 112);

        float4 v0 = *(const float4*)(cell +  0);
        float4 v1 = *(const float4*)(cell + 16);
        float4 v2 = *(const float4*)(cell + 32);
        float4 v3 = *(const float4*)(cell + 48);
        float4 v4 = *(const float4*)(cell + 64);
        float4 v5 = *(const float4*)(cell + 80);
        float4 v6 = *(const float4*)(cell + 96);

        float pdx = e1.x, pdy = e1.y, pdz = e1.z;
        float b1c = -SH_C1f * pdy;
        float b2c =  SH_C1f * pdz;
        float b3c = -SH_C1f * pdx;
        float b4c = C2_0f * pdx * pdy;
        float b5c = C2_1f * pdy * pdz;
        float b6c = C2_2f * (2.0f * pdz * pdz - pdx * pdx - pdy * pdy);
        float b7c = C2_3f * pdx * pdz;
        float b8c = C2_4f * (pdx * pdx - pdy * pdy);

        float cc0 = SH_C0f*v0.y + b1c*v0.z + b2c*v0.w + b3c*v1.x + b4c*v1.y
                  + b5c*v1.z + b6c*v1.w + b7c*v2.x + b8c*v2.y;
        float cc1 = SH_C0f*v2.z + b1c*v2.w + b2c*v3.x + b3c*v3.y + b4c*v3.z
                  + b5c*v3.w + b6c*v4.x + b7c*v4.y + b8c*v4.z;
        float cc2 = SH_C0f*v4.w + b1c*v5.x + b2c*v5.y + b3c*v5.z + b4c*v5.w
                  + b5c*v6.x + b6c*v6.y + b7c*v6.z + b8c*v6.w;
        cc0 *= wj; cc1 *= wj; cc2 *= wj;
        float ff0 = wj * v0.x;         // feat[0] partial (sum BEFORE relu)

        cc0 = dpp_add<0xB1>(cc0);  cc1 = dpp_add<0xB1>(cc1);
        cc2 = dpp_add<0xB1>(cc2);  ff0 = dpp_add<0xB1>(ff0);
        cc0 = dpp_add<0x4E>(cc0);  cc1 = dpp_add<0x4E>(cc1);
        cc2 = dpp_add<0x4E>(cc2);  ff0 = dpp_add<0x4E>(ff0);
        cc0 = dpp_add<0x141>(cc0); cc1 = dpp_add<0x141>(cc1);
        cc2 = dpp_add<0x141>(cc2); ff0 = dpp_add<0x141>(ff0);

        if (on && j < 4) {
            int pi = __float_as_int(e0.w);
            float rv = (j == 0) ? cc0 : (j == 1) ? cc1 : (j == 2) ? cc2
                                                      : fmaxf(ff0, 0.0f);
            size_t a = (j < 3) ? ((size_t)3 * pi + j) : ((size_t)3 * N + pi);
            out[a] = rv;
        }
    }
}

extern "C" void kernel_launch(void* const* d_in, const int* in_sizes, int n_in,
                              void* d_out, int out_size, void* d_ws, size_t ws_size,
                              hipStream_t stream) {
    const float* x     = (const float*)d_in[0];
    const float* d     = (const float*)d_in[1];
    const float* voxel = (const float*)d_in[2];
    float* out = (float*)d_out;
    int N = in_sizes[0] / 3;

    int grid = (N + PTS - 1) / PTS;
    plen_fused_kernel<<<grid, BLK, 0, stream>>>(x, d, voxel, out, N);
}

// Round 15
// 45.216 us; speedup vs baseline: 1.3425x; 1.0083x over previous
//
#include <hip/hip_runtime.h>

// Plenoxels: trilinear voxel interp (192^3 x 28 ch) + SH deg-2 eval.
// R15 = R14 with the two remaining occupancy caps removed:
//  - s_xbuf dropped (x staging was a null lever per R10) -> LDS 16KB ->
//    8 blocks/CU (wave-cap limited instead of LDS-limited)
//  - __launch_bounds__(256, 8): VGPR <= 64 -> 8 waves/SIMD possible
//  => true 32 waves/CU (vs R14's 28, R11's 12).
// Gather/SH/DPP reduce semantics identical to validated R11/R14.

#define VNL 192
#define BLK 256
#define WPB 4
#define TILES 2
#define PTS (BLK * TILES)   // 512 points per block

#define SH_C0f 0.28209479177387814f
#define SH_C1f 0.4886025119029199f
#define C2_0f  1.0925484305920792f
#define C2_1f (-1.0925484305920792f)
#define C2_2f  0.31539156525252005f
#define C2_3f (-1.0925484305920792f)
#define C2_4f  0.5462742152960396f

template <int CTRL>
__device__ __forceinline__ float dpp_add(float v) {
    int s = __builtin_amdgcn_update_dpp(0, __float_as_int(v), CTRL, 0xF, 0xF, true);
    return v + __int_as_float(s);
}

__global__ __launch_bounds__(BLK, 8) void plen_fused_kernel(
    const float* __restrict__ x,
    const float* __restrict__ d,
    const float* __restrict__ voxel,
    float* __restrict__ out,
    int N)
{
    __shared__ __align__(16) float4 s_pool[PTS][2];     // 16 KB record pool
    __shared__ unsigned s_wcnt[TILES][WPB];

    const int tid  = threadIdx.x;
    const int wid  = tid >> 6;
    const int lane = tid & 63;
    const int g = lane >> 3;   // group 0..7
    const int j = lane & 7;    // slot 0..7 within group
    const int base_i = blockIdx.x * PTS;
    const int rem = N - base_i;
    const bool full = (rem >= PTS);

    const float4 z4 = make_float4(0.f, 0.f, 0.f, 0.f);

    // ---- zero this block's output range (actives overwritten after barrier) --
    if (full && (((3 * base_i) & 3) == 0)) {
        float4* cf4 = reinterpret_cast<float4*>(out) + ((3 * base_i) >> 2);
        for (int k = tid; k < 3 * PTS / 4; k += BLK) cf4[k] = z4;   // 384 f4
    } else {
        int lim = 3 * (rem < PTS ? rem : PTS);
        for (int k = tid; k < lim; k += BLK) out[3 * base_i + k] = 0.f;
    }
    if (full && (((3 * (long long)N + base_i) & 3) == 0)) {
        float4* sf4 = reinterpret_cast<float4*>(out + (size_t)3 * N + base_i);
        for (int k = tid; k < PTS / 4; k += BLK) sf4[k] = z4;       // 128 f4
    } else {
        int lim = (rem < PTS ? rem : PTS);
        for (int k = tid; k < lim; k += BLK) out[(size_t)3 * N + base_i + k] = 0.f;
    }

    // ---- phase 1: mask + records (x scalar, d exec-masked) -----------------
    unsigned Mrun = 0;
    for (int t = 0; t < TILES; ++t) {
        int p = t * BLK + tid;
        int i = base_i + p;
        bool act = false;
        float ix = 0.f, iy = 0.f, iz = 0.f;
        float vdx = 0.f, vdy = 0.f, vdz = 0.f;
        if (i < N) {
            float px = x[3 * i + 0] / 1.5f;
            float py = x[3 * i + 1] / 1.5f;
            float pz = x[3 * i + 2] / 1.5f;
            act = (fabsf(px) < 0.5f) && (fabsf(py) < 0.5f) && (fabsf(pz) < 0.5f);
            if (act) {
                const float step = 2.0f / (float)VNL;
                ix = fminf(fmaxf(px / step + (float)(VNL / 2), 0.0f), (float)(VNL - 1));
                iy = fminf(fmaxf(py / step + (float)(VNL / 2), 0.0f), (float)(VNL - 1));
                iz = fminf(fmaxf(pz / step + (float)(VNL / 2), 0.0f), (float)(VNL - 1));
                vdx = d[3 * i + 0];
                vdy = d[3 * i + 1];
                vdz = d[3 * i + 2];
            }
        }

        unsigned long long bal = __ballot(act);
        unsigned wtot = (unsigned)__popcll(bal);
        unsigned pre  = (unsigned)__popcll(bal & ((1ull << lane) - 1ull));
        if (lane == 0) s_wcnt[t][wid] = wtot;
        __syncthreads();

        unsigned n0 = s_wcnt[t][0], n1 = s_wcnt[t][1];
        unsigned n2 = s_wcnt[t][2], n3 = s_wcnt[t][3];
        unsigned wbase = Mrun + (wid > 0 ? n0 : 0u) + (wid > 1 ? n1 : 0u)
                              + (wid > 2 ? n2 : 0u);
        if (act) {
            unsigned slot = wbase + pre;
            s_pool[slot][0] = make_float4(ix, iy, iz, __int_as_float(i));
            s_pool[slot][1] = make_float4(vdx, vdy, vdz, 0.f);
        }
        Mrun += n0 + n1 + n2 + n3;
    }
    __syncthreads();

    // ---- phase 2: z-pair gather + SH + DPP reduce (validated R11) ----------
    const unsigned M = Mrun;
    if (M == 0) return;
    const unsigned nch = (M + 7u) >> 3;

    // lane slot j -> original corner index j_old (preserves validated weights)
    const int jo = (int)((0x76425130u >> (4 * j)) & 7u);
    const int r  = j >> 1;      // z-pair run 0..3
    const int h  = j & 1;       // half within run (0: z=f2, 1: z=c2)

    for (unsigned c = (unsigned)wid; c < nch; c += WPB) {
        unsigned rr = c * 8u + (unsigned)g;
        bool on = (rr < M);
        unsigned rc = on ? rr : (M - 1u);

        float4 e0 = s_pool[rc][0];     // (ix,iy,iz, i)  LDS group-broadcast
        float4 e1 = s_pool[rc][1];     // (dx,dy,dz, -)

        float fx = floorf(e0.x), fy = floorf(e0.y), fz = floorf(e0.z);
        int f0 = (int)fx, f1 = (int)fy, f2 = (int)fz;
        int c0i = (int)ceilf(e0.x), c1i = (int)ceilf(e0.y), c2i = (int)ceilf(e0.z);
        float t0 = e0.x - fx, t1 = e0.y - fy, t2 = e0.z - fz;

        // validated non-standard weight pairing, keyed by original corner jo
        float wj = ((jo & 4) ? t2 : 1.0f - t2) * ((jo & 2) ? t1 : 1.0f - t1)
                 * ((jo & 1) ? t0 : 1.0f - t0);

        // run coords: X/Y per run table {(f,f),(c,f),(f,c),(c,c)}; z = f2 + h*(c2-f2)
        int X = (r & 1) ? c0i : f0;
        int Y = (r & 2) ? c1i : f1;
        const char* cell = (const char*)voxel
            + (size_t)(unsigned)(((X * VNL + Y) * VNL + f2) * 112 + h * (c2i - f2) * 112);

        float4 v0 = *(const float4*)(cell +  0);
        float4 v1 = *(const float4*)(cell + 16);
        float4 v2 = *(const float4*)(cell + 32);
        float4 v3 = *(const float4*)(cell + 48);
        float4 v4 = *(const float4*)(cell + 64);
        float4 v5 = *(const float4*)(cell + 80);
        float4 v6 = *(const float4*)(cell + 96);

        float pdx = e1.x, pdy = e1.y, pdz = e1.z;
        float b1c = -SH_C1f * pdy;
        float b2c =  SH_C1f * pdz;
        float b3c = -SH_C1f * pdx;
        float b4c = C2_0f * pdx * pdy;
        float b5c = C2_1f * pdy * pdz;
        float b6c = C2_2f * (2.0f * pdz * pdz - pdx * pdx - pdy * pdy);
        float b7c = C2_3f * pdx * pdz;
        float b8c = C2_4f * (pdx * pdx - pdy * pdy);

        float cc0 = SH_C0f*v0.y + b1c*v0.z + b2c*v0.w + b3c*v1.x + b4c*v1.y
                  + b5c*v1.z + b6c*v1.w + b7c*v2.x + b8c*v2.y;
        float cc1 = SH_C0f*v2.z + b1c*v2.w + b2c*v3.x + b3c*v3.y + b4c*v3.z
                  + b5c*v3.w + b6c*v4.x + b7c*v4.y + b8c*v4.z;
        float cc2 = SH_C0f*v4.w + b1c*v5.x + b2c*v5.y + b3c*v5.z + b4c*v5.w
                  + b5c*v6.x + b6c*v6.y + b7c*v6.z + b8c*v6.w;
        cc0 *= wj; cc1 *= wj; cc2 *= wj;
        float ff0 = wj * v0.x;         // feat[0] partial (sum BEFORE relu)

        cc0 = dpp_add<0xB1>(cc0);  cc1 = dpp_add<0xB1>(cc1);
        cc2 = dpp_add<0xB1>(cc2);  ff0 = dpp_add<0xB1>(ff0);
        cc0 = dpp_add<0x4E>(cc0);  cc1 = dpp_add<0x4E>(cc1);
        cc2 = dpp_add<0x4E>(cc2);  ff0 = dpp_add<0x4E>(ff0);
        cc0 = dpp_add<0x141>(cc0); cc1 = dpp_add<0x141>(cc1);
        cc2 = dpp_add<0x141>(cc2); ff0 = dpp_add<0x141>(ff0);

        if (on && j < 4) {
            int pi = __float_as_int(e0.w);
            float rv = (j == 0) ? cc0 : (j == 1) ? cc1 : (j == 2) ? cc2
                                                      : fmaxf(ff0, 0.0f);
            size_t a = (j < 3) ? ((size_t)3 * pi + j) : ((size_t)3 * N + pi);
            out[a] = rv;
        }
    }
}

extern "C" void kernel_launch(void* const* d_in, const int* in_sizes, int n_in,
                              void* d_out, int out_size, void* d_ws, size_t ws_size,
                              hipStream_t stream) {
    const float* x     = (const float*)d_in[0];
    const float* d     = (const float*)d_in[1];
    const float* voxel = (const float*)d_in[2];
    float* out = (float*)d_out;
    int N = in_sizes[0] / 3;

    int grid = (N + PTS - 1) / PTS;
    plen_fused_kernel<<<grid, BLK, 0, stream>>>(x, d, voxel, out, N);
}